// Round 1
// baseline (501.489 us; speedup 1.0000x reference)
//
#include <hip/hip_runtime.h>
#include <hip/hip_bf16.h>
#include <cstdint>

#define HDIM 256
#define CHUNK 1024

typedef __attribute__((ext_vector_type(8))) short bf16x8;
typedef __attribute__((ext_vector_type(4))) float f32x4;

__device__ __forceinline__ float bf2f(unsigned short u) {
    union { unsigned u; float f; } v; v.u = ((unsigned)u) << 16; return v.f;
}
__device__ __forceinline__ unsigned short f2bf(float f) {
    union { float f; unsigned u; } v; v.f = f;
    unsigned u = v.u;
    return (unsigned short)((u + 0x7fffu + ((u >> 16) & 1u)) >> 16);
}
__device__ __forceinline__ void gload_lds16(const void* g, void* l) {
    __builtin_amdgcn_global_load_lds((const __attribute__((address_space(1))) void*)g,
                                     (__attribute__((address_space(3))) void*)l, 16, 0, 0);
}
__device__ __forceinline__ float sigm(float x) { return 1.f / (1.f + expf(-x)); }

// ---- offsets via binary search (graph_id sorted) ----
__global__ void k_offsets(const int* __restrict__ gid, int* __restrict__ offs, int N, int B) {
    int g = blockIdx.x * blockDim.x + threadIdx.x;
    if (g > B) return;
    int lo = 0, hi = N;
    while (lo < hi) { int mid = (lo + hi) >> 1; if (gid[mid] < g) lo = mid + 1; else hi = mid; }
    offs[g] = lo;
}

// ---- cast nodes f32 -> bf16 ----
__global__ void k_cast_nodes(const float4* __restrict__ src, ushort4* __restrict__ dst, long n4) {
    long i = (long)blockIdx.x * blockDim.x + threadIdx.x;
    long stride = (long)gridDim.x * blockDim.x;
    for (; i < n4; i += stride) {
        float4 v = src[i];
        ushort4 o; o.x = f2bf(v.x); o.y = f2bf(v.y); o.z = f2bf(v.z); o.w = f2bf(v.w);
        dst[i] = o;
    }
}

// ---- weight prep: W0cat=[Wih0|Whh0] (1024x768) bf16, W1cat=[Wih1|Whh1] (1024x512) bf16 ----
__global__ void k_prep_w0(const float* __restrict__ Wih, const float* __restrict__ Whh,
                          unsigned short* __restrict__ W) {
    int idx = blockIdx.x * blockDim.x + threadIdx.x;
    if (idx >= 1024 * 768) return;
    int j = idx / 768, k = idx - j * 768;
    float v = (k < 512) ? Wih[j * 512 + k] : Whh[j * 256 + (k - 512)];
    W[idx] = f2bf(v);
}
__global__ void k_prep_w1(const float* __restrict__ Wih, const float* __restrict__ Whh,
                          unsigned short* __restrict__ W) {
    int idx = blockIdx.x * blockDim.x + threadIdx.x;
    if (idx >= 1024 * 512) return;
    int j = idx >> 9, k = idx & 511;
    float v = (k < 256) ? Wih[j * 256 + k] : Whh[j * 256 + (k - 256)];
    W[idx] = f2bf(v);
}
__global__ void k_prep_bias(const float* __restrict__ bih0, const float* __restrict__ bhh0,
                            const float* __restrict__ bih1, const float* __restrict__ bhh1,
                            float* __restrict__ b0, float* __restrict__ b1) {
    int idx = blockIdx.x * blockDim.x + threadIdx.x;
    if (idx < 1024) { b0[idx] = bih0[idx] + bhh0[idx]; b1[idx] = bih1[idx] + bhh1[idx]; }
}

// ---- attention + readout: one block per graph, online softmax over chunks ----
template<bool BF>
__global__ void __launch_bounds__(256) k_attn(const void* __restrict__ nodesv,
                                              const int* __restrict__ offs,
                                              const float* __restrict__ q,
                                              float* __restrict__ out,
                                              unsigned short* __restrict__ xb0) {
    const unsigned short* nb = (const unsigned short*)nodesv;
    const float* nf = (const float*)nodesv;
    int g = blockIdx.x;
    int t = threadIdx.x;
    int lane = t & 63, wid = t >> 6;
    int start = offs[g], end = offs[g + 1];
    __shared__ float qs[HDIM];
    __shared__ float es[CHUNK];
    __shared__ float redmax[4], redsum[4];
    float qv = q[(size_t)g * HDIM + t];
    qs[t] = qv;
    __syncthreads();
    float q0 = qs[lane * 4], q1 = qs[lane * 4 + 1], q2 = qs[lane * 4 + 2], q3 = qs[lane * 4 + 3];
    float m = -INFINITY, d = 0.f, racc = 0.f;
    for (int base = start; base < end; base += CHUNK) {
        int cn = min(CHUNK, end - base);
        // phase 1: each wave computes e for one node at a time
        for (int vi = wid; vi < cn; vi += 4) {
            size_t roff = (size_t)(base + vi) * HDIM;
            float e;
            if (BF) {
                ushort4 nv = *(const ushort4*)(nb + roff + lane * 4);
                e = q0 * bf2f(nv.x) + q1 * bf2f(nv.y) + q2 * bf2f(nv.z) + q3 * bf2f(nv.w);
            } else {
                float4 nv = *(const float4*)(nf + roff + lane * 4);
                e = q0 * nv.x + q1 * nv.y + q2 * nv.z + q3 * nv.w;
            }
#pragma unroll
            for (int o = 32; o >= 1; o >>= 1) e += __shfl_xor(e, o, 64);
            if (lane == 0) es[vi] = e;
        }
        __syncthreads();
        // chunk max
        float lm = -INFINITY;
        for (int k = t; k < cn; k += 256) lm = fmaxf(lm, es[k]);
#pragma unroll
        for (int o = 32; o >= 1; o >>= 1) lm = fmaxf(lm, __shfl_xor(lm, o, 64));
        if (lane == 0) redmax[wid] = lm;
        __syncthreads();
        float cmax = fmaxf(fmaxf(redmax[0], redmax[1]), fmaxf(redmax[2], redmax[3]));
        float nm = fmaxf(m, cmax);
        float scale = expf(m - nm);   // m=-inf -> 0
        racc *= scale; d *= scale; m = nm;
        // exp in place + sum
        float ls = 0.f;
        for (int k = t; k < cn; k += 256) { float wv = expf(es[k] - m); es[k] = wv; ls += wv; }
#pragma unroll
        for (int o = 32; o >= 1; o >>= 1) ls += __shfl_xor(ls, o, 64);
        if (lane == 0) redsum[wid] = ls;
        __syncthreads();
        d += redsum[0] + redsum[1] + redsum[2] + redsum[3];
        // phase 2: weighted accumulate; thread t owns feature t (rows hot in L2)
        for (int vi = 0; vi < cn; ++vi) {
            float wgt = es[vi];
            float nvt = BF ? bf2f(nb[(size_t)(base + vi) * HDIM + t])
                           : nf[(size_t)(base + vi) * HDIM + t];
            racc = fmaf(wgt, nvt, racc);
        }
        __syncthreads();
    }
    float r = (d > 0.f) ? racc / d : 0.f;
    size_t ob = (size_t)g * (2 * HDIM);
    out[ob + t] = qv;
    out[ob + HDIM + t] = r;
    size_t xb = (size_t)g * 768;
    xb0[xb + t] = f2bf(qv);
    xb0[xb + HDIM + t] = f2bf(r);
}

// ---- bf16 MFMA GEMM: C[M,1024] = A[M,K] * W[1024,K]^T  (128x128 tile, 4 waves) ----
template<int K>
__global__ void __launch_bounds__(256) k_gemm(const unsigned short* __restrict__ A,
                                              const unsigned short* __restrict__ Bm,
                                              float* __restrict__ C) {
    __shared__ unsigned short lA[128 * 32];
    __shared__ unsigned short lB[128 * 32];
    int t = threadIdx.x;
    int lane = t & 63;
    int wid = t >> 6;
    int wy = wid >> 1, wx = wid & 1;
    int brow = blockIdx.x * 128, bcol = blockIdx.y * 128;
    f32x4 acc[4][4];
#pragma unroll
    for (int i = 0; i < 4; ++i)
#pragma unroll
        for (int j = 0; j < 4; ++j) acc[i][j] = (f32x4){0.f, 0.f, 0.f, 0.f};
    int r0 = t >> 2, c0 = (t & 3) * 8;
    for (int k0 = 0; k0 < K; k0 += 32) {
        gload_lds16(A + (size_t)(brow + r0) * K + k0 + c0, lA + t * 8);
        gload_lds16(A + (size_t)(brow + 64 + r0) * K + k0 + c0, lA + 2048 + t * 8);
        gload_lds16(Bm + (size_t)(bcol + r0) * K + k0 + c0, lB + t * 8);
        gload_lds16(Bm + (size_t)(bcol + 64 + r0) * K + k0 + c0, lB + 2048 + t * 8);
        asm volatile("s_waitcnt vmcnt(0)" ::: "memory");
        __syncthreads();
        bf16x8 af[4], bfr[4];
#pragma unroll
        for (int mm = 0; mm < 4; ++mm)
            af[mm] = *(const bf16x8*)(lA + (wy * 64 + mm * 16 + (lane & 15)) * 32 + (lane >> 4) * 8);
#pragma unroll
        for (int nn = 0; nn < 4; ++nn)
            bfr[nn] = *(const bf16x8*)(lB + (wx * 64 + nn * 16 + (lane & 15)) * 32 + (lane >> 4) * 8);
#pragma unroll
        for (int mm = 0; mm < 4; ++mm)
#pragma unroll
            for (int nn = 0; nn < 4; ++nn)
                acc[mm][nn] = __builtin_amdgcn_mfma_f32_16x16x32_bf16(af[mm], bfr[nn], acc[mm][nn], 0, 0, 0);
        __syncthreads();
    }
    int orow = brow + wy * 64 + (lane >> 4) * 4;
    int ocol = bcol + wx * 64 + (lane & 15);
#pragma unroll
    for (int mm = 0; mm < 4; ++mm)
#pragma unroll
        for (int nn = 0; nn < 4; ++nn)
#pragma unroll
            for (int j = 0; j < 4; ++j)
                C[(size_t)(orow + mm * 16 + j) * 1024 + ocol + nn * 16] = acc[mm][nn][j];
}

// ---- LSTM elementwise updates ----
__global__ void k_lstm0(const float* __restrict__ gates, const float* __restrict__ bsum,
                        float* __restrict__ c, unsigned short* __restrict__ xb0,
                        unsigned short* __restrict__ xb1) {
    int idx = blockIdx.x * blockDim.x + threadIdx.x;
    int g = idx >> 8, j = idx & 255;
    const float* gr = gates + (size_t)g * 1024;
    float i_ = sigm(gr[j] + bsum[j]);
    float f_ = sigm(gr[256 + j] + bsum[256 + j]);
    float g_ = tanhf(gr[512 + j] + bsum[512 + j]);
    float o_ = sigm(gr[768 + j] + bsum[768 + j]);
    float cn = f_ * c[idx] + i_ * g_;
    float h = o_ * tanhf(cn);
    c[idx] = cn;
    unsigned short hb = f2bf(h);
    xb0[(size_t)g * 768 + 512 + j] = hb;
    xb1[(size_t)g * 512 + j] = hb;
}
__global__ void k_lstm1(const float* __restrict__ gates, const float* __restrict__ bsum,
                        float* __restrict__ c, float* __restrict__ q,
                        unsigned short* __restrict__ xb1) {
    int idx = blockIdx.x * blockDim.x + threadIdx.x;
    int g = idx >> 8, j = idx & 255;
    const float* gr = gates + (size_t)g * 1024;
    float i_ = sigm(gr[j] + bsum[j]);
    float f_ = sigm(gr[256 + j] + bsum[256 + j]);
    float g_ = tanhf(gr[512 + j] + bsum[512 + j]);
    float o_ = sigm(gr[768 + j] + bsum[768 + j]);
    float cn = f_ * c[idx] + i_ * g_;
    float h = o_ * tanhf(cn);
    c[idx] = cn;
    q[idx] = h;
    xb1[(size_t)g * 512 + 256 + j] = f2bf(h);
}

extern "C" void kernel_launch(void* const* d_in, const int* in_sizes, int n_in,
                              void* d_out, int out_size, void* d_ws, size_t ws_size,
                              hipStream_t stream) {
    const float* nodes = (const float*)d_in[0];
    const int* gid = (const int*)d_in[1];
    const float* Wih0 = (const float*)d_in[3];
    const float* Whh0 = (const float*)d_in[4];
    const float* bih0 = (const float*)d_in[5];
    const float* bhh0 = (const float*)d_in[6];
    const float* Wih1 = (const float*)d_in[7];
    const float* Whh1 = (const float*)d_in[8];
    const float* bih1 = (const float*)d_in[9];
    const float* bhh1 = (const float*)d_in[10];
    int N = in_sizes[0] / HDIM;
    int B = out_size / (2 * HDIM);
    float* out = (float*)d_out;

    const size_t AL = 512;
    auto rnd = [&](size_t b) { return (b + AL - 1) & ~(AL - 1); };
    size_t offs_b  = rnd((size_t)(B + 1) * 4);
    size_t q_b     = rnd((size_t)B * HDIM * 4);
    size_t xb0_b   = rnd((size_t)B * 768 * 2);
    size_t xb1_b   = rnd((size_t)B * 512 * 2);
    size_t gates_b = rnd((size_t)B * 1024 * 4);
    size_t w0_b    = rnd((size_t)1024 * 768 * 2);
    size_t w1_b    = rnd((size_t)1024 * 512 * 2);
    size_t bias_b  = rnd((size_t)1024 * 4);
    size_t nb_b    = rnd((size_t)N * HDIM * 2);
    size_t base_need = offs_b + 3 * q_b + xb0_b + xb1_b + 2 * gates_b + w0_b + w1_b + 2 * bias_b;
    bool useBF = (base_need + nb_b <= ws_size);

    char* w = (char*)d_ws;
    unsigned short* nodes_bf = nullptr;
    if (useBF) { nodes_bf = (unsigned short*)w; w += nb_b; }
    int* offs = (int*)w;               w += offs_b;
    float* q  = (float*)w;             w += q_b;
    float* c0 = (float*)w;             w += q_b;
    float* c1 = (float*)w;             w += q_b;
    unsigned short* xb0 = (unsigned short*)w; w += xb0_b;
    unsigned short* xb1 = (unsigned short*)w; w += xb1_b;
    float* gates0 = (float*)w;         w += gates_b;
    float* gates1 = (float*)w;         w += gates_b;
    unsigned short* W0 = (unsigned short*)w;  w += w0_b;
    unsigned short* W1 = (unsigned short*)w;  w += w1_b;
    float* b0 = (float*)w;             w += bias_b;
    float* b1 = (float*)w;             w += bias_b;

    hipMemsetAsync(q,  0, (size_t)B * HDIM * 4, stream);
    hipMemsetAsync(c0, 0, (size_t)B * HDIM * 4, stream);
    hipMemsetAsync(c1, 0, (size_t)B * HDIM * 4, stream);
    hipMemsetAsync(xb0, 0, (size_t)B * 768 * 2, stream);
    hipMemsetAsync(xb1, 0, (size_t)B * 512 * 2, stream);

    k_offsets<<<dim3((B + 256) / 256), dim3(256), 0, stream>>>(gid, offs, N, B);
    if (useBF) {
        long n4 = (long)N * (HDIM / 4);
        k_cast_nodes<<<dim3(2048), dim3(256), 0, stream>>>((const float4*)nodes, (ushort4*)nodes_bf, n4);
    }
    k_prep_w0<<<dim3((1024 * 768 + 255) / 256), dim3(256), 0, stream>>>(Wih0, Whh0, W0);
    k_prep_w1<<<dim3((1024 * 512 + 255) / 256), dim3(256), 0, stream>>>(Wih1, Whh1, W1);
    k_prep_bias<<<dim3(4), dim3(256), 0, stream>>>(bih0, bhh0, bih1, bhh1, b0, b1);

    for (int it = 0; it < 6; ++it) {
        if (useBF)
            k_attn<true><<<dim3(B), dim3(256), 0, stream>>>(nodes_bf, offs, q, out, xb0);
        else
            k_attn<false><<<dim3(B), dim3(256), 0, stream>>>(nodes, offs, q, out, xb0);
        if (it < 5) {
            k_gemm<768><<<dim3(B / 128, 8), dim3(256), 0, stream>>>(xb0, W0, gates0);
            k_lstm0<<<dim3(B), dim3(256), 0, stream>>>(gates0, b0, c0, xb0, xb1);
            k_gemm<512><<<dim3(B / 128, 8), dim3(256), 0, stream>>>(xb1, W1, gates1);
            k_lstm1<<<dim3(B), dim3(256), 0, stream>>>(gates1, b1, c1, q, xb1);
        }
    }
}